// Round 11
// baseline (185.986 us; speedup 1.0000x reference)
//
#include <hip/hip_runtime.h>

#define NPTS 1000000
#define FDIM 64
#define CNUM 128
#define PSTRIDE 8320          // 8192 sums (f-major [f*128+c]) + 128 counts
#define NB1 1024              // k1 grid: 4 blocks/CU
#define NB3 1024              // k3 grid: 4 blocks/CU

typedef _Float16 half8 __attribute__((ext_vector_type(8)));
typedef _Float16 half2v __attribute__((ext_vector_type(2)));
typedef float f32x4 __attribute__((ext_vector_type(4)));

// ---------------- K1: cluster sums via MFMA (onehot^T x X), f-half split ----------
// Round-6 structure: wave-pair shares a tile stream; wave handles f in [fh*32,+32).
// NEW: persists the f32->f16 conversions as a 128MB f16 cache (regular stores ->
// L3-allocating) in permuted pair layout: slot q = fh*16 + n15 of point p holds
// features (32fh + n15, 32fh + 16 + n15). Pass 2 reads HALF the bytes.
// Partials remain NONTEMPORAL (no L3 pollution).
__global__ __launch_bounds__(256, 4) void k1_partials(
    const float* __restrict__ feats, const int* __restrict__ labels,
    float* __restrict__ partials, half2v* __restrict__ f16c, int nblocks)
{
    __shared__ float lds[FDIM * 132];      // [f][c] padded to 132
    __shared__ float cnt[CNUM];
    const int tid = threadIdx.x;
    if (tid < CNUM) cnt[tid] = 0.f;
    __syncthreads();

    const int lane = tid & 63;
    const int n15 = lane & 15;
    const int kb = (lane >> 4) * 8;        // k-slot base
    const int rowb = (lane >> 4) * 4;      // C/D row base
    const int w = tid >> 6;
    const int fh = w & 1;                  // feature half
    const int fbase = fh * 32;
    const int nstreams = nblocks * 2;
    const int ts = ((blockIdx.x << 2) + w) >> 1;   // tile stream id

    f32x4 acc[8][2];
    #pragma unroll
    for (int ct = 0; ct < 8; ++ct)
        #pragma unroll
        for (int nt = 0; nt < 2; ++nt)
            acc[ct][nt] = (f32x4){0.f, 0.f, 0.f, 0.f};

    const int ntiles = NPTS / 32;          // 31250
    for (int t = ts; t < ntiles; t += nstreams) {
        const int p0 = t * 32;
        const float* fp = feats + (size_t)(p0 + kb) * FDIM + fbase + n15;
        const int* lp = labels + 2 * (p0 + kb) + 1;
        int vlab[8];
        #pragma unroll
        for (int i = 0; i < 8; ++i) vlab[i] = lp[2 * i];

        half8 B[2];
        #pragma unroll
        for (int i = 0; i < 8; ++i) {
            const float f0 = fp[i * FDIM];
            const float f1 = fp[i * FDIM + 16];
            half2v wv; wv[0] = (_Float16)f0; wv[1] = (_Float16)f1;
            B[0][i] = wv[0]; B[1][i] = wv[1];
            f16c[(size_t)(p0 + kb + i) * 32 + fh * 16 + n15] = wv;  // 64B/row coalesced
        }
        // counts: fh==0 waves only, one lane-op per point
        if (fh == 0 && lane < 32) {
            const int myl = labels[2 * (p0 + lane) + 1];
            atomicAdd(&cnt[myl], 1.0f);
        }
        #pragma unroll
        for (int ct = 0; ct < 8; ++ct) {
            const int cmine = ct * 16 + n15;
            union { unsigned u[4]; half8 h; } ua;
            #pragma unroll
            for (int j = 0; j < 4; ++j)
                ua.u[j] = ((vlab[2 * j] == cmine) ? 0x3C00u : 0u)
                        | ((vlab[2 * j + 1] == cmine) ? 0x3C000000u : 0u);
            #pragma unroll
            for (int nt = 0; nt < 2; ++nt)
                acc[ct][nt] = __builtin_amdgcn_mfma_f32_16x16x32_f16(
                    ua.h, B[nt], acc[ct][nt], 0, 0, 0);
        }
    }
    __syncthreads();

    // 2-round merge: waves 0,1 write (disjoint f-halves); waves 2,3 add.
    for (int r = 0; r < 2; ++r) {
        if ((w >> 1) == r) {
            #pragma unroll
            for (int ct = 0; ct < 8; ++ct)
                #pragma unroll
                for (int nt = 0; nt < 2; ++nt) {
                    float* a = &lds[(fbase + nt * 16 + n15) * 132 + ct * 16 + rowb];
                    if (r == 0) *(f32x4*)a = acc[ct][nt];
                    else        *(f32x4*)a = *(f32x4*)a + acc[ct][nt];
                }
        }
        __syncthreads();
    }

    // nontemporal writeout of partials (don't evict the f16 cache from L3)
    float* dst = partials + (size_t)blockIdx.x * PSTRIDE;
    for (int i4 = tid; i4 < 2048; i4 += 256) {        // float4 units, f-major
        const int f = i4 >> 5, c0 = (i4 & 31) * 4;
        __builtin_nontemporal_store(*(const f32x4*)&lds[f * 132 + c0],
                                    (f32x4*)dst + i4);
    }
    if (tid < CNUM)
        __builtin_nontemporal_store(cnt[tid], &dst[8192 + tid]);
}

// ---------------- K2: reduce partials -> red (nontemporal reads) ----------------
// red[0..8191] c-major [c*64+f]; red[8192..8319] counts.
__global__ __launch_bounds__(256) void k2_reduce(
    const float* __restrict__ partials, int nblocks, float* __restrict__ red,
    float* __restrict__ ppsum, float* __restrict__ dsum, int* __restrict__ counter)
{
    const int tid = threadIdx.x;
    const int tsub = tid & 31, grp = tid >> 5;
    const int t0 = blockIdx.x * 32;                 // 260 blocks cover 8320
    float s = 0.f;
    #pragma unroll 8
    for (int b = grp; b < nblocks; b += 8)
        s += __builtin_nontemporal_load(&partials[(size_t)b * PSTRIDE + t0 + tsub]);
    __shared__ float lred[8][33];
    lred[grp][tsub] = s;
    __syncthreads();
    if (tid < 32) {
        float tot = 0.f;
        #pragma unroll
        for (int q = 0; q < 8; ++q) tot += lred[q][tid];
        const int t = t0 + tid;
        if (t < 8192) red[(t & 127) * FDIM + (t >> 7)] = tot;  // f-major -> c-major
        else red[t] = tot;
    }
    if (blockIdx.x == 0) {
        if (tid >= 128) ppsum[tid - 128] = 0.f;
        if (tid == 64) dsum[0] = 0.f;
        if (tid == 65) counter[0] = 0;
    }
}

// ---------------- K3: variance term from the f16 cache (half traffic) ------------
// 32-pt tiles (4KB): lane l, chunk s loads half8 #(s*64+l) -> point 8s+(l>>3),
// pair-slots 4*(l&7)..+3. Means in LDS in the SAME permuted pair order,
// stride 68 floats per c so bank = (4c + 8*l8 + j) % 32 spreads by cluster.
// Reverse traversal: the cache tail (written last by k1) is L3-resident.
__global__ __launch_bounds__(256, 4) void k3_var(
    const half8* __restrict__ f16c, const int* __restrict__ labels,
    const float* __restrict__ red, float* __restrict__ ppsum, int nblocks)
{
    __shared__ float mu[CNUM * 68];   // permuted pairs: mu[c*68 + q*2 + r]
    __shared__ float lpp[CNUM];
    const int tid = threadIdx.x;
    for (int idx = tid; idx < CNUM * 32; idx += 256) {
        const int c = idx >> 5, q = idx & 31;
        const int flo = ((q >> 4) << 5) + (q & 15);   // feature of pair-lo
        const float inv = 1.0f / red[8192 + c];
        mu[c * 68 + q * 2]     = red[c * 64 + flo] * inv;
        mu[c * 68 + q * 2 + 1] = red[c * 64 + flo + 16] * inv;
    }
    if (tid < CNUM) lpp[tid] = 0.f;
    __syncthreads();

    const int lane = tid & 63;
    const int l8 = lane & 7, pgrp = lane >> 3;
    const int nwaves = nblocks * 4;
    const int wid = ((blockIdx.x << 8) + tid) >> 6;
    const int ntiles = NPTS / 32;           // 31250

    int b = ntiles - 1 - wid;
    half8 v[4]; int cc = 0;
    if (b >= 0) {
        const half8* fp = f16c + (size_t)b * 256 + lane;
        #pragma unroll
        for (int s = 0; s < 4; ++s) v[s] = fp[s * 64];   // 1KB coalesced each
        cc = labels[2 * (b * 32 + (lane & 31)) + 1];
    }
    while (b >= 0) {
        const int bn = b - nwaves;
        half8 vn[4]; int ccn = 0;
        if (bn >= 0) {
            const half8* fp = f16c + (size_t)bn * 256 + lane;
            #pragma unroll
            for (int s = 0; s < 4; ++s) vn[s] = fp[s * 64];
            ccn = labels[2 * (bn * 32 + (lane & 31)) + 1];
        }
        #pragma unroll
        for (int s = 0; s < 4; ++s) {
            const int c = __shfl(cc, 8 * s + pgrp);
            const float* m = &mu[c * 68 + l8 * 8];     // 16B-aligned (68 = 4*17)
            const f32x4 m0 = *(const f32x4*)m;
            const f32x4 m1 = *(const f32x4*)(m + 4);
            float d0 = (float)v[s][0] - m0[0], d1 = (float)v[s][1] - m0[1];
            float d2 = (float)v[s][2] - m0[2], d3 = (float)v[s][3] - m0[3];
            float sq = d0 * d0 + d1 * d1 + d2 * d2 + d3 * d3;
            d0 = (float)v[s][4] - m1[0]; d1 = (float)v[s][5] - m1[1];
            d2 = (float)v[s][6] - m1[2]; d3 = (float)v[s][7] - m1[3];
            sq += d0 * d0 + d1 * d1 + d2 * d2 + d3 * d3;
            sq += __shfl_xor(sq, 1);
            sq += __shfl_xor(sq, 2);
            sq += __shfl_xor(sq, 4);
            if (l8 == 0) {
                const float t = sqrtf(sq) - 0.5f;      // DELTA_VAR
                if (t > 0.f) atomicAdd(&lpp[c], t * t);
            }
        }
        b = bn;
        #pragma unroll
        for (int s = 0; s < 4; ++s) v[s] = vn[s];
        cc = ccn;
    }
    __syncthreads();
    if (tid < CNUM) atomicAdd(&ppsum[tid], lpp[tid]);
}

// ---------------- K45: pairwise dist loss + last-block finalize ----------------
__global__ __launch_bounds__(128) void k45_dist_final(
    const float* __restrict__ red, const float* __restrict__ ppsum,
    float* __restrict__ dsum, int* __restrict__ counter, float* __restrict__ out)
{
    __shared__ float4 mu4[CNUM * 17];   // padded: lanes read different rows
    __shared__ int lastflag;
    __shared__ float sv[2];
    const int tid = threadIdx.x;
    for (int i = tid; i < 2048; i += 128) {
        float4 s4 = ((const float4*)red)[i];
        float ci = 1.0f / red[8192 + (i >> 4)];
        mu4[(i >> 4) * 17 + (i & 15)] =
            make_float4(s4.x * ci, s4.y * ci, s4.z * ci, s4.w * ci);
    }
    __syncthreads();
    const int i = blockIdx.x, j = tid;
    float sq = 0.f;
    #pragma unroll
    for (int q = 0; q < 16; ++q) {
        float4 a = mu4[i * 17 + q], b = mu4[j * 17 + q];
        float dx = a.x - b.x, dy = a.y - b.y, dz = a.z - b.z, dw = a.w - b.w;
        sq += dx * dx + dy * dy + dz * dz + dw * dw;
    }
    float dl = 0.f;
    if (j != i) {
        const float r = 3.0f - sqrtf(sq);   // DELTA_DIST
        if (r > 0.f) dl = r * r;
    }
    #pragma unroll
    for (int m = 1; m < 64; m <<= 1) dl += __shfl_xor(dl, m);
    if ((tid & 63) == 0) atomicAdd(dsum, dl);
    __threadfence();
    __syncthreads();
    if (tid == 0) lastflag = (atomicAdd(counter, 1) == (int)gridDim.x - 1);
    __syncthreads();
    if (lastflag) {
        float v = ppsum[tid] / red[8192 + tid];
        #pragma unroll
        for (int m = 1; m < 64; m <<= 1) v += __shfl_xor(v, m);
        if ((tid & 63) == 0) sv[tid >> 6] = v;
    }
    __syncthreads();
    if (lastflag && tid == 0) {
        const float dtot = atomicAdd(dsum, 0.0f);   // device-scope read
        out[0] = (sv[0] + sv[1]) / (float)CNUM
               + dtot / (float)(CNUM * (CNUM - 1));
    }
}

extern "C" void kernel_launch(void* const* d_in, const int* in_sizes, int n_in,
                              void* d_out, int out_size, void* d_ws, size_t ws_size,
                              hipStream_t stream) {
    (void)in_sizes; (void)n_in; (void)out_size;
    const float* feats   = (const float*)d_in[0];
    const int* labels    = (const int*)d_in[1];
    float* ws            = (float*)d_ws;
    float* out           = (float*)d_out;

    const size_t f16_bytes = (size_t)NPTS * 32 * sizeof(half2v);   // 128 MB
    int nb1 = NB1;
    {
        const size_t tail = (size_t)(PSTRIDE + 130) * 4 + 32 + f16_bytes;
        if (ws_size > tail) {
            size_t cap = (ws_size - tail) / ((size_t)PSTRIDE * 4);
            if ((size_t)nb1 > cap) nb1 = (int)cap;
        } else nb1 = 1;
        if (nb1 < 1) nb1 = 1;
    }
    float* partials = ws;
    float* red      = ws + (size_t)nb1 * PSTRIDE;   // 16B-aligned
    float* ppsum    = red + PSTRIDE;
    float* dsum     = ppsum + 128;
    int*   counter  = (int*)(dsum + 1);
    const size_t fixed_bytes = ((size_t)nb1 * PSTRIDE + PSTRIDE + 128 + 2) * 4;
    half2v* f16c = (half2v*)((char*)d_ws + ((fixed_bytes + 15) & ~(size_t)15));

    k1_partials<<<nb1, 256, 0, stream>>>(feats, labels, partials, f16c, nb1);
    k2_reduce<<<PSTRIDE / 32, 256, 0, stream>>>(partials, nb1, red, ppsum, dsum, counter);
    k3_var<<<NB3, 256, 0, stream>>>((const half8*)f16c, labels, red, ppsum, NB3);
    k45_dist_final<<<CNUM, 128, 0, stream>>>(red, ppsum, dsum, counter, out);
}

// Round 12
// 134.179 us; speedup vs baseline: 1.3861x; 1.3861x over previous
//
#include <hip/hip_runtime.h>

#define NPTS 1000000
#define FDIM 64
#define CNUM 128
#define NTILES 31250          // NPTS / 32
#define PSTRIDE 8320          // 8192 sums (c-major [c*64+f]) + 128 counts
#define NB1 1024              // k1 grid: 4 blocks/CU
#define NB3 1024              // k3 grid: 4 blocks/CU

typedef _Float16 half8 __attribute__((ext_vector_type(8)));
typedef float f32x4 __attribute__((ext_vector_type(4)));

// ---------------- K1: cluster sums via MFMA (onehot^T x X), LDS-transposed ------
// One 32-pt tile per block-iteration. Each lane loads 2 float4 (16B/lane, 1KB/instr
// coalesced), waves stage the 32x64 f32 tile in LDS (pitch 66: write 2-way, read
// 2-way bank aliasing = free), then wave (fh,ch) computes clusters [64ch,64ch+64)
// x features [32fh,32fh+32): acc[4][2] = 32 VGPR, one-hot built 4x/wave (16/tile
// total, same as round 6), 8 MFMA/wave/tile. Register prefetch of tile t+nb
// overlaps HBM latency with MFMA. Partials written c-major direct from registers
// (waves disjoint in (c,f) -> no LDS merge), nontemporal.
__global__ __launch_bounds__(256, 4) void k1_partials(
    const float4* __restrict__ feats4, const int* __restrict__ labels,
    float* __restrict__ partials, int nblocks)
{
    __shared__ float tile[32][66];
    __shared__ float cnt[CNUM];
    const int tid = threadIdx.x;
    if (tid < CNUM) cnt[tid] = 0.f;

    const int lane = tid & 63;
    const int n15 = lane & 15;
    const int g = lane >> 4;
    const int kb = g * 8;                  // k-slot base (fragment rows)
    const int rowb = g * 4;                // C/D row base
    const int w = tid >> 6;
    const int fh = w & 1, ch = w >> 1;
    const int fbase = fh * 32;
    const int cbase = ch * 64;
    const int pr0 = w * 8 + g;             // LDS rows this lane stages
    const int c4 = n15 * 4;

    f32x4 acc[4][2];
    #pragma unroll
    for (int ct = 0; ct < 4; ++ct)
        #pragma unroll
        for (int nt = 0; nt < 2; ++nt)
            acc[ct][nt] = (f32x4){0.f, 0.f, 0.f, 0.f};

    int t = blockIdx.x;
    float4 r0, r1; int vl[8]; int cl = 0;
    if (t < NTILES) {
        const int p0 = t * 32;
        r0 = feats4[(size_t)(p0 + pr0) * 16 + n15];
        r1 = feats4[(size_t)(p0 + pr0 + 4) * 16 + n15];
        const int* lp = labels + 2 * (p0 + kb) + 1;
        #pragma unroll
        for (int i = 0; i < 8; ++i) vl[i] = lp[2 * i];
        if (w == 0 && lane < 32) cl = labels[2 * (p0 + lane) + 1];
    }
    __syncthreads();                       // cnt init visible; safe to write tile

    while (t < NTILES) {
        *(f32x4*)&tile[pr0][c4]     = *(const f32x4*)&r0;
        *(f32x4*)&tile[pr0 + 4][c4] = *(const f32x4*)&r1;
        __syncthreads();                   // tile staged

        const int tn = t + nblocks;
        float4 q0, q1; int vl2[8]; int cl2 = 0;
        if (tn < NTILES) {                 // issue next tile's loads early (T14)
            const int p0 = tn * 32;
            q0 = feats4[(size_t)(p0 + pr0) * 16 + n15];
            q1 = feats4[(size_t)(p0 + pr0 + 4) * 16 + n15];
            const int* lp = labels + 2 * (p0 + kb) + 1;
            #pragma unroll
            for (int i = 0; i < 8; ++i) vl2[i] = lp[2 * i];
            if (w == 0 && lane < 32) cl2 = labels[2 * (p0 + lane) + 1];
        }
        if (w == 0 && lane < 32) atomicAdd(&cnt[cl], 1.0f);

        // B fragments from LDS (16 x ds_read_b32, 2-way aliasing = free)
        half8 B[2];
        #pragma unroll
        for (int i = 0; i < 8; ++i) {
            B[0][i] = (_Float16)tile[kb + i][fbase + n15];
            B[1][i] = (_Float16)tile[kb + i][fbase + 16 + n15];
        }
        // one-hot for my 4 cluster-tiles + 2 MFMAs each
        #pragma unroll
        for (int ct = 0; ct < 4; ++ct) {
            const int cmine = cbase + ct * 16 + n15;
            union { unsigned u[4]; half8 h; } ua;
            #pragma unroll
            for (int j = 0; j < 4; ++j)
                ua.u[j] = ((vl[2 * j] == cmine) ? 0x3C00u : 0u)
                        | ((vl[2 * j + 1] == cmine) ? 0x3C000000u : 0u);
            #pragma unroll
            for (int nt = 0; nt < 2; ++nt)
                acc[ct][nt] = __builtin_amdgcn_mfma_f32_16x16x32_f16(
                    ua.h, B[nt], acc[ct][nt], 0, 0, 0);
        }
        __syncthreads();                   // reads done before next write
        t = tn;
        r0 = q0; r1 = q1;
        #pragma unroll
        for (int i = 0; i < 8; ++i) vl[i] = vl2[i];
        cl = cl2;
    }

    // direct register -> global writeout, c-major [c*64+f]; waves disjoint.
    float* dst = partials + (size_t)blockIdx.x * PSTRIDE;
    #pragma unroll
    for (int ct = 0; ct < 4; ++ct)
        #pragma unroll
        for (int nt = 0; nt < 2; ++nt)
            #pragma unroll
            for (int reg = 0; reg < 4; ++reg) {
                const int c = cbase + ct * 16 + rowb + reg;
                const int f = fbase + nt * 16 + n15;
                __builtin_nontemporal_store(acc[ct][nt][reg], &dst[c * FDIM + f]);
            }
    if (tid < CNUM)
        __builtin_nontemporal_store(cnt[tid], &dst[8192 + tid]);
}

// ---------------- K2: reduce partials -> red (nontemporal reads) ----------------
// Partials and red both c-major: pure columnwise sum, no transpose.
__global__ __launch_bounds__(256) void k2_reduce(
    const float* __restrict__ partials, int nblocks, float* __restrict__ red,
    float* __restrict__ ppsum, float* __restrict__ dsum, int* __restrict__ counter)
{
    const int tid = threadIdx.x;
    const int tsub = tid & 31, grp = tid >> 5;
    const int t0 = blockIdx.x * 32;                 // 260 blocks cover 8320
    float s = 0.f;
    #pragma unroll 8
    for (int b = grp; b < nblocks; b += 8)
        s += __builtin_nontemporal_load(&partials[(size_t)b * PSTRIDE + t0 + tsub]);
    __shared__ float lred[8][33];
    lred[grp][tsub] = s;
    __syncthreads();
    if (tid < 32) {
        float tot = 0.f;
        #pragma unroll
        for (int q = 0; q < 8; ++q) tot += lred[q][tid];
        red[t0 + tid] = tot;
    }
    if (blockIdx.x == 0) {
        if (tid >= 128) ppsum[tid - 128] = 0.f;
        if (tid == 64) dsum[0] = 0.f;
        if (tid == 65) counter[0] = 0;
    }
}

// ---------------- K3: variance term (REVERSE traversal for L3 reuse) -------------
__global__ __launch_bounds__(256, 4) void k3_var(
    const float4* __restrict__ feats4, const int* __restrict__ labels,
    const float* __restrict__ red, float* __restrict__ ppsum, int nblocks)
{
    __shared__ float4 mu4[CNUM * 16];   // [c][16] (quarter-wave shares c: no pad)
    __shared__ float lpp[CNUM];
    const int tid = threadIdx.x;
    for (int i = tid; i < 2048; i += 256) {
        float4 sv = ((const float4*)red)[i];
        float ci = 1.0f / red[8192 + (i >> 4)];
        mu4[i] = make_float4(sv.x * ci, sv.y * ci, sv.z * ci, sv.w * ci);
    }
    if (tid < CNUM) lpp[tid] = 0.f;
    __syncthreads();

    const int lane = tid & 63;
    const int k = lane & 15, g = lane >> 4;
    const int nwaves = nblocks * 4;
    const int wid = ((blockIdx.x << 8) + tid) >> 6;
    const int ntiles = NPTS / 16;           // 62500 tiles of 16 points

    // reverse: start at the tail (most recently L3-cached by k1), walk backward
    int b = ntiles - 1 - wid;
    float4 v[4]; int cc = 0;
    if (b >= 0) {
        const float4* fp = feats4 + (size_t)b * 256 + lane;
        #pragma unroll
        for (int s = 0; s < 4; ++s) v[s] = fp[s * 64];
        cc = labels[2 * (b * 16 + k) + 1];
    }
    while (b >= 0) {
        const int bn = b - nwaves;
        float4 vn[4]; int ccn = 0;
        if (bn >= 0) {
            const float4* fp = feats4 + (size_t)bn * 256 + lane;
            #pragma unroll
            for (int s = 0; s < 4; ++s) vn[s] = fp[s * 64];
            ccn = labels[2 * (bn * 16 + k) + 1];
        }
        #pragma unroll
        for (int s = 0; s < 4; ++s) {
            const int c = __shfl(cc, 4 * s + g);
            float4 m = mu4[c * 16 + k];
            float dx = v[s].x - m.x, dy = v[s].y - m.y,
                  dz = v[s].z - m.z, dw = v[s].w - m.w;
            float sq = dx * dx + dy * dy + dz * dz + dw * dw;
            sq += __shfl_xor(sq, 1); sq += __shfl_xor(sq, 2);
            sq += __shfl_xor(sq, 4); sq += __shfl_xor(sq, 8);
            if (k == 0) {
                const float t = sqrtf(sq) - 0.5f;      // DELTA_VAR
                if (t > 0.f) atomicAdd(&lpp[c], t * t);
            }
        }
        b = bn;
        #pragma unroll
        for (int s = 0; s < 4; ++s) v[s] = vn[s];
        cc = ccn;
    }
    __syncthreads();
    if (tid < CNUM) atomicAdd(&ppsum[tid], lpp[tid]);
}

// ---------------- K45: pairwise dist loss + last-block finalize ----------------
__global__ __launch_bounds__(128) void k45_dist_final(
    const float* __restrict__ red, const float* __restrict__ ppsum,
    float* __restrict__ dsum, int* __restrict__ counter, float* __restrict__ out)
{
    __shared__ float4 mu4[CNUM * 17];   // padded: lanes read different rows
    __shared__ int lastflag;
    __shared__ float sv[2];
    const int tid = threadIdx.x;
    for (int i = tid; i < 2048; i += 128) {
        float4 s4 = ((const float4*)red)[i];
        float ci = 1.0f / red[8192 + (i >> 4)];
        mu4[(i >> 4) * 17 + (i & 15)] =
            make_float4(s4.x * ci, s4.y * ci, s4.z * ci, s4.w * ci);
    }
    __syncthreads();
    const int i = blockIdx.x, j = tid;
    float sq = 0.f;
    #pragma unroll
    for (int q = 0; q < 16; ++q) {
        float4 a = mu4[i * 17 + q], b = mu4[j * 17 + q];
        float dx = a.x - b.x, dy = a.y - b.y, dz = a.z - b.z, dw = a.w - b.w;
        sq += dx * dx + dy * dy + dz * dz + dw * dw;
    }
    float dl = 0.f;
    if (j != i) {
        const float r = 3.0f - sqrtf(sq);   // DELTA_DIST
        if (r > 0.f) dl = r * r;
    }
    #pragma unroll
    for (int m = 1; m < 64; m <<= 1) dl += __shfl_xor(dl, m);
    if ((tid & 63) == 0) atomicAdd(dsum, dl);
    __threadfence();
    __syncthreads();
    if (tid == 0) lastflag = (atomicAdd(counter, 1) == (int)gridDim.x - 1);
    __syncthreads();
    if (lastflag) {
        float v = ppsum[tid] / red[8192 + tid];
        #pragma unroll
        for (int m = 1; m < 64; m <<= 1) v += __shfl_xor(v, m);
        if ((tid & 63) == 0) sv[tid >> 6] = v;
    }
    __syncthreads();
    if (lastflag && tid == 0) {
        const float dtot = atomicAdd(dsum, 0.0f);   // device-scope read
        out[0] = (sv[0] + sv[1]) / (float)CNUM
               + dtot / (float)(CNUM * (CNUM - 1));
    }
}

extern "C" void kernel_launch(void* const* d_in, const int* in_sizes, int n_in,
                              void* d_out, int out_size, void* d_ws, size_t ws_size,
                              hipStream_t stream) {
    (void)in_sizes; (void)n_in; (void)out_size;
    const float4* feats4 = (const float4*)d_in[0];
    const int* labels    = (const int*)d_in[1];
    float* ws            = (float*)d_ws;
    float* out           = (float*)d_out;

    int nb1 = NB1;
    {
        size_t avail = ws_size / sizeof(float);
        size_t fixed = PSTRIDE + 128 + 2;           // red + ppsum + dsum + counter
        if (avail > fixed) {
            size_t cap = (avail - fixed) / PSTRIDE;
            if ((size_t)nb1 > cap) nb1 = (int)cap;
        } else nb1 = 1;
        if (nb1 < 1) nb1 = 1;
    }
    float* partials = ws;
    float* red      = ws + (size_t)nb1 * PSTRIDE;   // 16B-aligned
    float* ppsum    = red + PSTRIDE;
    float* dsum     = ppsum + 128;
    int*   counter  = (int*)(dsum + 1);

    k1_partials<<<nb1, 256, 0, stream>>>(feats4, labels, partials, nb1);
    k2_reduce<<<PSTRIDE / 32, 256, 0, stream>>>(partials, nb1, red, ppsum, dsum, counter);
    k3_var<<<NB3, 256, 0, stream>>>(feats4, labels, red, ppsum, NB3);
    k45_dist_final<<<CNUM, 128, 0, stream>>>(red, ppsum, dsum, counter, out);
}